// Round 5
// baseline (436.791 us; speedup 1.0000x reference)
//
#include <hip/hip_runtime.h>
#include <hip/hip_cooperative_groups.h>

namespace cg = cooperative_groups;

typedef unsigned short u16;
typedef float f32x4 __attribute__((ext_vector_type(4)));
typedef short bf16x8 __attribute__((ext_vector_type(8)));

constexpr int Bn = 4, Ln = 512, Mn = 32, EMBn = 512, Hn = 8, HSn = 64;
constexpr int Rn = Mn * Hn; // 256

__device__ __forceinline__ float wave_sum(float v) {
#pragma unroll
  for (int off = 1; off < 64; off <<= 1) v += __shfl_xor(v, off, 64);
  return v;
}
__device__ __forceinline__ float wave_max(float v) {
#pragma unroll
  for (int off = 1; off < 64; off <<= 1) v = fmaxf(v, __shfl_xor(v, off, 64));
  return v;
}
__device__ __forceinline__ u16 f2bf(float f) {
  unsigned u = __float_as_uint(f);
  unsigned r = (u + 0x7FFFu + ((u >> 16) & 1u)) >> 16;
  return (u16)r;
}
__device__ __forceinline__ unsigned pack2(float a, float b) {
  return (unsigned)f2bf(a) | ((unsigned)f2bf(b) << 16);
}

// ---------------------------------------------------------------------------
// MFMA GEMM core: C tile 32x64 = A[32xK] * B^T[64xK], K=512, strides 512.
// LDS-staged, double-buffered, XOR-swizzled. 256 threads. (proven in R2/R3)
// ---------------------------------------------------------------------------
template <bool BIAS>
__device__ __forceinline__ void gemm_core(const u16* __restrict__ Ag,
                                          const u16* __restrict__ Bg,
                                          float* __restrict__ Cg,
                                          const float* __restrict__ pbv,
                                          int r0, int n0, int tid,
                                          u16* smem) {
  const int wave = tid >> 6, lane = tid & 63;
  const int srow = lane >> 3, sblk = lane & 7;
  const u16* gsrc0;
  const u16* gsrc1;
  const u16* gsrc2;
  unsigned lofs0, lofs1, lofs2, lstep0, lstep1, lstep2;
  {
    int id0 = wave * 3;
#pragma unroll
    for (int q = 0; q < 3; ++q) {
      int id = id0 + q;
      const u16* g;
      unsigned lo, ls;
      if (id < 4) {
        int row = id * 8 + srow;
        g = Ag + (size_t)(r0 + row) * 512 + sblk * 8;
        lo = row * 64 + (((sblk * 16) ^ ((row & 7) << 4)) >> 1);
        ls = 2048;
      } else {
        int row = (id - 4) * 8 + srow;
        g = Bg + (size_t)(n0 + row) * 512 + sblk * 8;
        lo = 4096 + row * 64 + (((sblk * 16) ^ ((row & 7) << 4)) >> 1);
        ls = 4096;
      }
      if (q == 0) { gsrc0 = g; lofs0 = lo; lstep0 = ls; }
      else if (q == 1) { gsrc1 = g; lofs1 = lo; lstep1 = ls; }
      else { gsrc2 = g; lofs2 = lo; lstep2 = ls; }
    }
  }
  uint4 rv0 = *(const uint4*)gsrc0;
  uint4 rv1 = *(const uint4*)gsrc1;
  uint4 rv2 = *(const uint4*)gsrc2;
  *(uint4*)&smem[lofs0] = rv0;
  *(uint4*)&smem[lofs1] = rv1;
  *(uint4*)&smem[lofs2] = rv2;
  __syncthreads();

  f32x4 acc0 = {0.f, 0.f, 0.f, 0.f};
  f32x4 acc1 = {0.f, 0.f, 0.f, 0.f};
  const int ra = (wave >> 1) * 16 + (lane & 15);
  const int nb = (wave & 1) * 32 + (lane & 15);
  const unsigned asw = (unsigned)((ra & 7) << 4);
  const unsigned bsw = (unsigned)((nb & 7) << 4);
  const unsigned kg = (unsigned)((lane >> 4) * 16);

#pragma unroll
  for (int c = 0; c < 8; ++c) {
    const int cur = c & 1;
    if (c < 7) {
      rv0 = *(const uint4*)(gsrc0 + (c + 1) * 64);
      rv1 = *(const uint4*)(gsrc1 + (c + 1) * 64);
      rv2 = *(const uint4*)(gsrc2 + (c + 1) * 64);
    }
    const char* Ab = (const char*)(smem + cur * 2048);
    const char* Bb = (const char*)(smem + 4096 + cur * 4096);
#pragma unroll
    for (int ks = 0; ks < 2; ++ks) {
      unsigned kb = ks * 64 + kg;
      bf16x8 a = *(const bf16x8*)(Ab + ra * 128 + (kb ^ asw));
      bf16x8 b0 = *(const bf16x8*)(Bb + nb * 128 + (kb ^ bsw));
      bf16x8 b1 = *(const bf16x8*)(Bb + (nb + 16) * 128 + (kb ^ bsw));
      acc0 = __builtin_amdgcn_mfma_f32_16x16x32_bf16(a, b0, acc0, 0, 0, 0);
      acc1 = __builtin_amdgcn_mfma_f32_16x16x32_bf16(a, b1, acc1, 0, 0, 0);
    }
    if (c < 7) {
      unsigned bo = (unsigned)(cur ^ 1);
      *(uint4*)&smem[lofs0 + bo * lstep0] = rv0;
      *(uint4*)&smem[lofs1 + bo * lstep1] = rv1;
      *(uint4*)&smem[lofs2 + bo * lstep2] = rv2;
    }
    __syncthreads();
  }

  const int rg = r0 + (wave >> 1) * 16 + ((lane >> 4) << 2);
  const int cg = n0 + (wave & 1) * 32 + (lane & 15);
#pragma unroll
  for (int j = 0; j < 4; ++j) {
    float v0 = acc0[j], v1 = acc1[j];
    if (BIAS) {
      float pv = pbv[rg + j];
      v0 = (v0 + pv) * 0.125f;
      v1 = (v1 + pv) * 0.125f;
    }
    Cg[(size_t)(rg + j) * 512 + cg] = v0;
    Cg[(size_t)(rg + j) * 512 + cg + 16] = v1;
  }
}

// ---------------------------------------------------------------------------
// Cooperative mega-kernel: 512 blocks x 256 threads, 2 blocks/CU.
// Phases: A) LN + P-proj  B) score GEMM + h-transpose  C) softmax
//         D) gmat GEMM    E) out reduction.
// ---------------------------------------------------------------------------
__global__ __launch_bounds__(256, 2) void mega_kernel(
    const float* __restrict__ x, const float* __restrict__ gam,
    const float* __restrict__ bet, const float* __restrict__ cells,
    const float* __restrict__ q_w, const float* __restrict__ q_b,
    const float* __restrict__ v, const float* __restrict__ vbp,
    u16* __restrict__ hb, u16* __restrict__ htb, u16* __restrict__ Pb,
    float* __restrict__ pb, float* __restrict__ S, u16* __restrict__ Wb,
    float* __restrict__ G, float* __restrict__ out) {
  __shared__ __align__(16) char SMEM[24576];
  cg::grid_group grid = cg::this_grid();
  const int bid = blockIdx.x, tid = threadIdx.x;
  const int wid = tid >> 6, lane = tid & 63;

  // ---------------- Phase A: LN (vb 0..511) + P projection (vb 512..767)
  for (int vblk = bid; vblk < 768; vblk += 512) {
    if (vblk < 512) {
      int row = vblk * 4 + wid;
      const float* xr = x + (size_t)row * EMBn + lane * 8;
      float4 a0 = *(const float4*)xr;
      float4 a1 = *(const float4*)(xr + 4);
      float s = a0.x + a0.y + a0.z + a0.w + a1.x + a1.y + a1.z + a1.w;
      float ss = a0.x * a0.x + a0.y * a0.y + a0.z * a0.z + a0.w * a0.w +
                 a1.x * a1.x + a1.y * a1.y + a1.z * a1.z + a1.w * a1.w;
      s = wave_sum(s);
      ss = wave_sum(ss);
      float mu = s * (1.0f / EMBn);
      float var = ss * (1.0f / EMBn) - mu * mu;
      float rstd = rsqrtf(var + 1e-5f);
      const float* gp = gam + lane * 8;
      const float* bp = bet + lane * 8;
      float4 g0 = *(const float4*)gp, g1 = *(const float4*)(gp + 4);
      float4 b0 = *(const float4*)bp, b1 = *(const float4*)(bp + 4);
      float4 o0, o1;
      o0.x = (a0.x - mu) * rstd * g0.x + b0.x;
      o0.y = (a0.y - mu) * rstd * g0.y + b0.y;
      o0.z = (a0.z - mu) * rstd * g0.z + b0.z;
      o0.w = (a0.w - mu) * rstd * g0.w + b0.w;
      o1.x = (a1.x - mu) * rstd * g1.x + b1.x;
      o1.y = (a1.y - mu) * rstd * g1.y + b1.y;
      o1.z = (a1.z - mu) * rstd * g1.z + b1.z;
      o1.w = (a1.w - mu) * rstd * g1.w + b1.w;
      uint4 st;
      st.x = pack2(o0.x, o0.y);
      st.y = pack2(o0.z, o0.w);
      st.z = pack2(o1.x, o1.y);
      st.w = pack2(o1.z, o1.w);
      *(uint4*)&hb[(size_t)row * EMBn + lane * 8] = st;
    } else {
      int r = vblk - 512;
      int hh = r & 7;
      float* cs = (float*)SMEM;
      if (tid < HSn) cs[tid] = cells[(size_t)r * HSn + tid];
      __syncthreads();
      for (int e = tid; e < EMBn; e += 256) {
        float acc = 0.f;
#pragma unroll 8
        for (int s2 = 0; s2 < HSn; ++s2)
          acc += cs[s2] * q_w[(size_t)(hh * HSn + s2) * EMBn + e];
        Pb[(size_t)r * EMBn + e] = f2bf(acc);
      }
      if (tid == 0) {
        float a = 0.f;
        for (int s2 = 0; s2 < HSn; ++s2) a += cs[s2] * q_b[hh * HSn + s2];
        pb[r] = a;
      }
      __syncthreads();
    }
  }
  __threadfence();
  grid.sync();

  // ---------------- Phase B: score GEMM (bid<256) + transpose (bid>=256)
  if (bid < 256) {
    int b = bid >> 6, rem = bid & 63;
    int r0 = (rem >> 3) * 32, l0 = (rem & 7) * 64;
    gemm_core<true>(Pb, hb + (size_t)b * Ln * EMBn, S + (size_t)b * Rn * Ln,
                    pb, r0, l0, tid, (u16*)SMEM);
  } else {
    int t = bid - 256;
    int b = t >> 6, rem = t & 63;
    int l0 = (rem >> 3) * 64, j0 = (rem & 7) * 64;
    u16(*ts)[65] = (u16(*)[65])SMEM;
#pragma unroll
    for (int i = 0; i < 4; ++i) {
      int idx = tid + i * 256;
      int row = idx >> 4, c4 = (idx & 15) * 4;
      uint2 u = *(const uint2*)&hb[(size_t)(b * Ln + l0 + row) * EMBn + j0 + c4];
      ts[row][c4] = (u16)(u.x & 0xffffu);
      ts[row][c4 + 1] = (u16)(u.x >> 16);
      ts[row][c4 + 2] = (u16)(u.y & 0xffffu);
      ts[row][c4 + 3] = (u16)(u.y >> 16);
    }
    __syncthreads();
#pragma unroll
    for (int i = 0; i < 4; ++i) {
      int idx = tid + i * 256;
      int jr = idx >> 4, lc4 = (idx & 15) * 4;
      unsigned lo = (unsigned)ts[lc4][jr] | ((unsigned)ts[lc4 + 1][jr] << 16);
      unsigned hi = (unsigned)ts[lc4 + 2][jr] | ((unsigned)ts[lc4 + 3][jr] << 16);
      uint2 u;
      u.x = lo;
      u.y = hi;
      *(uint2*)&htb[(size_t)(b * EMBn + j0 + jr) * Ln + l0 + lc4] = u;
    }
  }
  __threadfence();
  grid.sync();

  // ---------------- Phase C: softmax (1024 rows, one wave each)
  {
    int gw = bid * 4 + wid;
    if (gw < Bn * Rn) {
      const float* sr = S + (size_t)gw * Ln + lane * 8;
      float4 a0 = *(const float4*)sr;
      float4 a1 = *(const float4*)(sr + 4);
      float mx = fmaxf(fmaxf(fmaxf(a0.x, a0.y), fmaxf(a0.z, a0.w)),
                       fmaxf(fmaxf(a1.x, a1.y), fmaxf(a1.z, a1.w)));
      mx = wave_max(mx);
      a0.x = __expf(a0.x - mx); a0.y = __expf(a0.y - mx);
      a0.z = __expf(a0.z - mx); a0.w = __expf(a0.w - mx);
      a1.x = __expf(a1.x - mx); a1.y = __expf(a1.y - mx);
      a1.z = __expf(a1.z - mx); a1.w = __expf(a1.w - mx);
      float s = a0.x + a0.y + a0.z + a0.w + a1.x + a1.y + a1.z + a1.w;
      s = wave_sum(s);
      float inv = 1.0f / s;
      uint4 st;
      st.x = pack2(a0.x * inv, a0.y * inv);
      st.y = pack2(a0.z * inv, a0.w * inv);
      st.z = pack2(a1.x * inv, a1.y * inv);
      st.w = pack2(a1.z * inv, a1.w * inv);
      *(uint4*)&Wb[(size_t)gw * Ln + lane * 8] = st;
    }
  }
  __threadfence();
  grid.sync();

  // ---------------- Phase D: gmat GEMM (bid<256)
  if (bid < 256) {
    int b = bid >> 6, rem = bid & 63;
    int r0 = (rem >> 3) * 32, j0 = (rem & 7) * 64;
    gemm_core<false>(Wb + (size_t)b * Rn * Ln, htb + (size_t)b * EMBn * Ln,
                     G + (size_t)b * Rn * EMBn, nullptr, r0, j0, tid,
                     (u16*)SMEM);
  }
  __threadfence();
  grid.sync();

  // ---------------- Phase E: out (1024 vblocks, 2 per real block)
  float(*Gs)[EMBn] = (float(*)[EMBn])SMEM; // 8 KiB
#pragma unroll
  for (int it = 0; it < 2; ++it) {
    if (it) __syncthreads(); // protect Gs reuse
    int vblk = bid + it * 512;
    int sc = vblk & 3, hh = (vblk >> 2) & 7, m = vblk >> 5;
    int r = m * Hn + hh;
#pragma unroll
    for (int i = 0; i < 2; ++i) {
      int idx4 = tid + i * 256;
      int bb = idx4 >> 7, e4 = (idx4 & 127) << 2;
      *(float4*)&Gs[bb][e4] =
          *(const float4*)&G[((size_t)bb * Rn + r) * EMBn + e4];
    }
    __syncthreads();
#pragma unroll
    for (int i = 0; i < 4; ++i) {
      int rr = sc * 16 + wid * 4 + i;
      const float* vr =
          v + ((size_t)m * EMBn + hh * HSn + rr) * EMBn + lane * 8;
      float4 v0 = *(const float4*)vr;
      float4 v1 = *(const float4*)(vr + 4);
      float acc[Bn];
#pragma unroll
      for (int bb = 0; bb < Bn; ++bb) {
        const float* gp = &Gs[bb][lane * 8];
        float4 g0 = *(const float4*)gp;
        float4 g1 = *(const float4*)(gp + 4);
        acc[bb] = v0.x * g0.x + v0.y * g0.y + v0.z * g0.z + v0.w * g0.w +
                  v1.x * g1.x + v1.y * g1.y + v1.z * g1.z + v1.w * g1.w;
      }
#pragma unroll
      for (int off = 1; off < 64; off <<= 1) {
#pragma unroll
        for (int bb = 0; bb < Bn; ++bb) acc[bb] += __shfl_xor(acc[bb], off, 64);
      }
      if (lane == 0) {
        float vbv = vbp[(size_t)m * EMBn + hh * HSn + rr];
#pragma unroll
        for (int bb = 0; bb < Bn; ++bb) {
          out[(((size_t)bb * Hn + hh) * Mn + m) * HSn + rr] = acc[bb] + vbv;
        }
      }
    }
  }
}

extern "C" void kernel_launch(void* const* d_in, const int* in_sizes, int n_in,
                              void* d_out, int out_size, void* d_ws,
                              size_t ws_size, hipStream_t stream) {
  const float* x = (const float*)d_in[0];
  const float* cells = (const float*)d_in[1];
  const float* q_w = (const float*)d_in[2];
  const float* q_b = (const float*)d_in[3];
  const float* v = (const float*)d_in[4];
  const float* vbp = (const float*)d_in[5];
  const float* ln_g = (const float*)d_in[6];
  const float* ln_b = (const float*)d_in[7];
  float* out = (float*)d_out;

  u16* hb = (u16*)d_ws;                             // 2 MB
  u16* htb = hb + (size_t)Bn * Ln * EMBn;           // 2 MB
  u16* Pb = htb + (size_t)Bn * Ln * EMBn;           // 256 KB
  u16* Wb = Pb + (size_t)Rn * EMBn;                 // 1 MB
  float* pb = (float*)(Wb + (size_t)Bn * Rn * Ln);  // 1 KB
  float* S = pb + Rn;                               // 2 MB
  float* G = S + (size_t)Bn * Rn * Ln;              // 2 MB

  void* args[] = {&x,  &ln_g, &ln_b, &cells, &q_w, &q_b, &v, &vbp,
                  &hb, &htb,  &Pb,   &pb,    &S,   &Wb,  &G, &out};
  hipLaunchCooperativeKernel((const void*)mega_kernel, dim3(512), dim3(256),
                             args, 0, stream);
}

// Round 6
// 176.817 us; speedup vs baseline: 2.4703x; 2.4703x over previous
//
#include <hip/hip_runtime.h>

typedef unsigned short u16;
typedef float f32x4 __attribute__((ext_vector_type(4)));
typedef short bf16x8 __attribute__((ext_vector_type(8)));

constexpr int Bn = 4, Ln = 512, Mn = 32, EMBn = 512, Hn = 8, HSn = 64;
constexpr int Rn = Mn * Hn; // 256
constexpr int NBLK = 512;
constexpr size_t BAR_OFF = 12u << 20;

__device__ __forceinline__ float wave_sum(float v) {
#pragma unroll
  for (int off = 1; off < 64; off <<= 1) v += __shfl_xor(v, off, 64);
  return v;
}
__device__ __forceinline__ u16 f2bf(float f) {
  unsigned u = __float_as_uint(f);
  unsigned r = (u + 0x7FFFu + ((u >> 16) & 1u)) >> 16;
  return (u16)r;
}
__device__ __forceinline__ unsigned pack2(float a, float b) {
  return (unsigned)f2bf(a) | ((unsigned)f2bf(b) << 16);
}

// Hand-rolled grid barrier: generation counter + arrival count, agent scope.
__device__ __forceinline__ void gbar(unsigned* cnt, unsigned* gen) {
  __syncthreads();
  if (threadIdx.x == 0) {
    __threadfence();
    unsigned g0 = __hip_atomic_load(gen, __ATOMIC_ACQUIRE,
                                    __HIP_MEMORY_SCOPE_AGENT);
    unsigned arr = __hip_atomic_fetch_add(cnt, 1u, __ATOMIC_ACQ_REL,
                                          __HIP_MEMORY_SCOPE_AGENT);
    if (arr == (unsigned)(NBLK - 1)) {
      __hip_atomic_store(cnt, 0u, __ATOMIC_RELAXED, __HIP_MEMORY_SCOPE_AGENT);
      __hip_atomic_fetch_add(gen, 1u, __ATOMIC_RELEASE,
                             __HIP_MEMORY_SCOPE_AGENT);
    } else {
      unsigned g;
      do {
        __builtin_amdgcn_s_sleep(2);
        g = __hip_atomic_load(gen, __ATOMIC_ACQUIRE, __HIP_MEMORY_SCOPE_AGENT);
      } while (g == g0);
    }
  }
  __syncthreads();
}

// ---------------------------------------------------------------------------
// MFMA GEMM core: C tile 32x64 = A[32xK] * B^T[64xK], K=512, strides 512.
// LDS-staged, double-buffered, XOR-swizzled. 256 threads. (proven R2/R3)
// ---------------------------------------------------------------------------
template <bool BIAS>
__device__ __forceinline__ void gemm_core(const u16* __restrict__ Ag,
                                          const u16* __restrict__ Bg,
                                          float* __restrict__ Cg,
                                          const float* __restrict__ pbv,
                                          int r0, int n0, int tid,
                                          u16* smem) {
  const int wave = tid >> 6, lane = tid & 63;
  const int srow = lane >> 3, sblk = lane & 7;
  const u16* gsrc0;
  const u16* gsrc1;
  const u16* gsrc2;
  unsigned lofs0, lofs1, lofs2, lstep0, lstep1, lstep2;
  {
    int id0 = wave * 3;
#pragma unroll
    for (int q = 0; q < 3; ++q) {
      int id = id0 + q;
      const u16* g;
      unsigned lo, ls;
      if (id < 4) {
        int row = id * 8 + srow;
        g = Ag + (size_t)(r0 + row) * 512 + sblk * 8;
        lo = row * 64 + (((sblk * 16) ^ ((row & 7) << 4)) >> 1);
        ls = 2048;
      } else {
        int row = (id - 4) * 8 + srow;
        g = Bg + (size_t)(n0 + row) * 512 + sblk * 8;
        lo = 4096 + row * 64 + (((sblk * 16) ^ ((row & 7) << 4)) >> 1);
        ls = 4096;
      }
      if (q == 0) { gsrc0 = g; lofs0 = lo; lstep0 = ls; }
      else if (q == 1) { gsrc1 = g; lofs1 = lo; lstep1 = ls; }
      else { gsrc2 = g; lofs2 = lo; lstep2 = ls; }
    }
  }
  uint4 rv0 = *(const uint4*)gsrc0;
  uint4 rv1 = *(const uint4*)gsrc1;
  uint4 rv2 = *(const uint4*)gsrc2;
  *(uint4*)&smem[lofs0] = rv0;
  *(uint4*)&smem[lofs1] = rv1;
  *(uint4*)&smem[lofs2] = rv2;
  __syncthreads();

  f32x4 acc0 = {0.f, 0.f, 0.f, 0.f};
  f32x4 acc1 = {0.f, 0.f, 0.f, 0.f};
  const int ra = (wave >> 1) * 16 + (lane & 15);
  const int nb = (wave & 1) * 32 + (lane & 15);
  const unsigned asw = (unsigned)((ra & 7) << 4);
  const unsigned bsw = (unsigned)((nb & 7) << 4);
  const unsigned kg = (unsigned)((lane >> 4) * 16);

#pragma unroll
  for (int c = 0; c < 8; ++c) {
    const int cur = c & 1;
    if (c < 7) {
      rv0 = *(const uint4*)(gsrc0 + (c + 1) * 64);
      rv1 = *(const uint4*)(gsrc1 + (c + 1) * 64);
      rv2 = *(const uint4*)(gsrc2 + (c + 1) * 64);
    }
    const char* Ab = (const char*)(smem + cur * 2048);
    const char* Bb = (const char*)(smem + 4096 + cur * 4096);
#pragma unroll
    for (int ks = 0; ks < 2; ++ks) {
      unsigned kb = ks * 64 + kg;
      bf16x8 a = *(const bf16x8*)(Ab + ra * 128 + (kb ^ asw));
      bf16x8 b0 = *(const bf16x8*)(Bb + nb * 128 + (kb ^ bsw));
      bf16x8 b1 = *(const bf16x8*)(Bb + (nb + 16) * 128 + (kb ^ bsw));
      acc0 = __builtin_amdgcn_mfma_f32_16x16x32_bf16(a, b0, acc0, 0, 0, 0);
      acc1 = __builtin_amdgcn_mfma_f32_16x16x32_bf16(a, b1, acc1, 0, 0, 0);
    }
    if (c < 7) {
      unsigned bo = (unsigned)(cur ^ 1);
      *(uint4*)&smem[lofs0 + bo * lstep0] = rv0;
      *(uint4*)&smem[lofs1 + bo * lstep1] = rv1;
      *(uint4*)&smem[lofs2 + bo * lstep2] = rv2;
    }
    __syncthreads();
  }

  const int rg = r0 + (wave >> 1) * 16 + ((lane >> 4) << 2);
  const int cg = n0 + (wave & 1) * 32 + (lane & 15);
#pragma unroll
  for (int j = 0; j < 4; ++j) {
    float v0 = acc0[j], v1 = acc1[j];
    if (BIAS) {
      float pv = pbv[rg + j];
      v0 = (v0 + pv) * 0.125f;
      v1 = (v1 + pv) * 0.125f;
    }
    Cg[(size_t)(rg + j) * 512 + cg] = v0;
    Cg[(size_t)(rg + j) * 512 + cg + 16] = v1;
  }
}

// ---------------------------------------------------------------------------
// Persistent kernel: 512 blocks x 256 threads (cooperative for residency).
// Phases: A) LN + P-proj | bar | B) score GEMM + h-transpose | bar |
//         C) fused softmax + gmat (16-row groups, 512 blocks).
// ---------------------------------------------------------------------------
__global__ __launch_bounds__(256, 2) void persist_kernel(
    const float* __restrict__ x, const float* __restrict__ gam,
    const float* __restrict__ bet, const float* __restrict__ cells,
    const float* __restrict__ q_w, const float* __restrict__ q_b,
    u16* __restrict__ hb, u16* __restrict__ htb, u16* __restrict__ Pb,
    float* __restrict__ pb, float* __restrict__ S, float* __restrict__ G,
    unsigned* __restrict__ bar) {
  __shared__ __align__(16) char SMEM[32768];
  const int bid = blockIdx.x, tid = threadIdx.x;
  const int wid = tid >> 6, lane = tid & 63;
  unsigned* cnt = bar;
  unsigned* gen = bar + 32;

  // ---------------- Phase A: LN (vblk 0..511) + P projection (512..767)
  for (int vblk = bid; vblk < 768; vblk += 512) {
    if (vblk < 512) {
      int row = vblk * 4 + wid;
      const float* xr = x + (size_t)row * EMBn + lane * 8;
      float4 a0 = *(const float4*)xr;
      float4 a1 = *(const float4*)(xr + 4);
      float s = a0.x + a0.y + a0.z + a0.w + a1.x + a1.y + a1.z + a1.w;
      float ss = a0.x * a0.x + a0.y * a0.y + a0.z * a0.z + a0.w * a0.w +
                 a1.x * a1.x + a1.y * a1.y + a1.z * a1.z + a1.w * a1.w;
      s = wave_sum(s);
      ss = wave_sum(ss);
      float mu = s * (1.0f / EMBn);
      float var = ss * (1.0f / EMBn) - mu * mu;
      float rstd = rsqrtf(var + 1e-5f);
      const float* gp = gam + lane * 8;
      const float* bp = bet + lane * 8;
      float4 g0 = *(const float4*)gp, g1 = *(const float4*)(gp + 4);
      float4 b0 = *(const float4*)bp, b1 = *(const float4*)(bp + 4);
      float4 o0, o1;
      o0.x = (a0.x - mu) * rstd * g0.x + b0.x;
      o0.y = (a0.y - mu) * rstd * g0.y + b0.y;
      o0.z = (a0.z - mu) * rstd * g0.z + b0.z;
      o0.w = (a0.w - mu) * rstd * g0.w + b0.w;
      o1.x = (a1.x - mu) * rstd * g1.x + b1.x;
      o1.y = (a1.y - mu) * rstd * g1.y + b1.y;
      o1.z = (a1.z - mu) * rstd * g1.z + b1.z;
      o1.w = (a1.w - mu) * rstd * g1.w + b1.w;
      uint4 st;
      st.x = pack2(o0.x, o0.y);
      st.y = pack2(o0.z, o0.w);
      st.z = pack2(o1.x, o1.y);
      st.w = pack2(o1.z, o1.w);
      *(uint4*)&hb[(size_t)row * EMBn + lane * 8] = st;
    } else {
      int r = vblk - 512;
      int hh = r & 7;
      float* cs = (float*)SMEM;
      if (tid < HSn) cs[tid] = cells[(size_t)r * HSn + tid];
      __syncthreads();
      for (int e = tid; e < EMBn; e += 256) {
        float acc = 0.f;
#pragma unroll 8
        for (int s2 = 0; s2 < HSn; ++s2)
          acc += cs[s2] * q_w[(size_t)(hh * HSn + s2) * EMBn + e];
        Pb[(size_t)r * EMBn + e] = f2bf(acc);
      }
      if (tid == 0) {
        float a = 0.f;
        for (int s2 = 0; s2 < HSn; ++s2) a += cs[s2] * q_b[hh * HSn + s2];
        pb[r] = a;
      }
      __syncthreads();
    }
  }
  gbar(cnt, gen);

  // ---------------- Phase B: score GEMM (bid<256) + transpose (bid>=256)
  if (bid < 256) {
    int b = bid >> 6, rem = bid & 63;
    int r0 = (rem >> 3) * 32, l0 = (rem & 7) * 64;
    gemm_core<true>(Pb, hb + (size_t)b * Ln * EMBn, S + (size_t)b * Rn * Ln,
                    pb, r0, l0, tid, (u16*)SMEM);
  } else {
    int t = bid - 256;
    int b = t >> 6, rem = t & 63;
    int l0 = (rem >> 3) * 64, j0 = (rem & 7) * 64;
    u16(*ts)[65] = (u16(*)[65])SMEM;
#pragma unroll
    for (int i = 0; i < 4; ++i) {
      int idx = tid + i * 256;
      int row = idx >> 4, c4 = (idx & 15) * 4;
      uint2 u = *(const uint2*)&hb[(size_t)(b * Ln + l0 + row) * EMBn + j0 + c4];
      ts[row][c4] = (u16)(u.x & 0xffffu);
      ts[row][c4 + 1] = (u16)(u.x >> 16);
      ts[row][c4 + 2] = (u16)(u.y & 0xffffu);
      ts[row][c4 + 3] = (u16)(u.y >> 16);
    }
    __syncthreads();
#pragma unroll
    for (int i = 0; i < 4; ++i) {
      int idx = tid + i * 256;
      int jr = idx >> 4, lc4 = (idx & 15) * 4;
      unsigned lo = (unsigned)ts[lc4][jr] | ((unsigned)ts[lc4 + 1][jr] << 16);
      unsigned hi = (unsigned)ts[lc4 + 2][jr] | ((unsigned)ts[lc4 + 3][jr] << 16);
      uint2 u;
      u.x = lo;
      u.y = hi;
      *(uint2*)&htb[(size_t)(b * EMBn + j0 + jr) * Ln + l0 + lc4] = u;
    }
  }
  gbar(cnt, gen);

  // ---------------- Phase C: fused softmax + gmat, 16-row groups.
  {
    int b = bid >> 7, rem = bid & 127;
    int r0 = (rem >> 3) * 16, j0 = (rem & 7) * 64;
    u16* Wlds = (u16*)SMEM;          // [16][512] bf16 swizzled, 16 KiB
    char* Bl = SMEM + 16384;         // 2 x [64][64] bf16 swizzled, 16 KiB
    // softmax: 16 threads per row, 32 vals each
    {
      int row = tid >> 4, sub = tid & 15;
      const float* sp = S + ((size_t)b * Rn + r0 + row) * Ln + sub * 32;
      float4 vv[8];
#pragma unroll
      for (int i = 0; i < 8; ++i) vv[i] = *(const float4*)(sp + i * 4);
      float mx = -1e30f;
#pragma unroll
      for (int i = 0; i < 8; ++i)
        mx = fmaxf(mx, fmaxf(fmaxf(vv[i].x, vv[i].y), fmaxf(vv[i].z, vv[i].w)));
#pragma unroll
      for (int off = 1; off < 16; off <<= 1)
        mx = fmaxf(mx, __shfl_xor(mx, off, 64));
      float sum = 0.f;
#pragma unroll
      for (int i = 0; i < 8; ++i) {
        vv[i].x = __expf(vv[i].x - mx);
        vv[i].y = __expf(vv[i].y - mx);
        vv[i].z = __expf(vv[i].z - mx);
        vv[i].w = __expf(vv[i].w - mx);
        sum += vv[i].x + vv[i].y + vv[i].z + vv[i].w;
      }
#pragma unroll
      for (int off = 1; off < 16; off <<= 1) sum += __shfl_xor(sum, off, 64);
      float inv = 1.0f / sum;
      unsigned swz = (unsigned)((row & 7) << 4);
      char* wbase = (char*)Wlds + row * 1024;
#pragma unroll
      for (int q = 0; q < 4; ++q) {
        uint4 st;
        st.x = pack2(vv[2 * q].x * inv, vv[2 * q].y * inv);
        st.y = pack2(vv[2 * q].z * inv, vv[2 * q].w * inv);
        st.z = pack2(vv[2 * q + 1].x * inv, vv[2 * q + 1].y * inv);
        st.w = pack2(vv[2 * q + 1].z * inv, vv[2 * q + 1].w * inv);
        *(uint4*)(wbase + (((unsigned)(sub * 64 + q * 16)) ^ swz)) = st;
      }
    }
    // B staging init (chunk 0)
    int brow = tid >> 2, bks = (tid & 3) * 2;
    const u16* bg = htb + ((size_t)b * EMBn + j0 + brow) * Ln + bks * 8;
    unsigned bswz = (unsigned)((brow & 7) << 4);
    unsigned bofs0 = brow * 128 + (((unsigned)(bks * 16)) ^ bswz);
    unsigned bofs1 = brow * 128 + (((unsigned)(bks * 16 + 16)) ^ bswz);
    uint4 rv0 = *(const uint4*)bg;
    uint4 rv1 = *(const uint4*)(bg + 8);
    *(uint4*)(Bl + bofs0) = rv0;
    *(uint4*)(Bl + bofs1) = rv1;
    __syncthreads();

    const int wave = tid >> 6;
    const int lr = lane & 15;
    const unsigned lg = (unsigned)(lane >> 4);
    f32x4 acc = {0.f, 0.f, 0.f, 0.f};
    const unsigned asw = (unsigned)((lr & 7) << 4);
    const int jloc = wave * 16 + lr;
    const unsigned bsw2 = (unsigned)((jloc & 7) << 4);
    const char* Abase = (const char*)Wlds + lr * 1024;
#pragma unroll
    for (int c = 0; c < 8; ++c) {
      const int cur = c & 1;
      if (c < 7) {
        rv0 = *(const uint4*)(bg + (c + 1) * 64);
        rv1 = *(const uint4*)(bg + (c + 1) * 64 + 8);
      }
      const char* Bb = Bl + cur * 8192;
#pragma unroll
      for (int ks = 0; ks < 2; ++ks) {
        unsigned kbA = (unsigned)(c * 128 + ks * 64) + lg * 16;
        unsigned kbB = (unsigned)(ks * 64) + lg * 16;
        bf16x8 a = *(const bf16x8*)(Abase + (kbA ^ asw));
        bf16x8 bb = *(const bf16x8*)(Bb + jloc * 128 + (kbB ^ bsw2));
        acc = __builtin_amdgcn_mfma_f32_16x16x32_bf16(a, bb, acc, 0, 0, 0);
      }
      if (c < 7) {
        char* Bo = Bl + (cur ^ 1) * 8192;
        *(uint4*)(Bo + bofs0) = rv0;
        *(uint4*)(Bo + bofs1) = rv1;
      }
      __syncthreads();
    }
    const int rg = r0 + (int)lg * 4;
    const int cg = j0 + jloc;
#pragma unroll
    for (int i = 0; i < 4; ++i) {
      G[((size_t)b * Rn + rg + i) * EMBn + cg] = acc[i];
    }
  }
}

// ---------------------------------------------------------------------------
// out[b,(m,h),s] = dot(v[m, h*64+s, :], G[b, r, :]) + vb[m, h*64+s]
// ---------------------------------------------------------------------------
__global__ __launch_bounds__(256) void out_kernel(
    const float* __restrict__ v, const float* __restrict__ vb,
    const float* __restrict__ G, float* __restrict__ out) {
  int bid = blockIdx.x;
  int sc = bid & 3, hh = (bid >> 2) & 7, m = bid >> 5;
  int r = m * Hn + hh;
  __shared__ float Gs[Bn][EMBn]; // 8 KiB
  int tid = threadIdx.x;
#pragma unroll
  for (int i = 0; i < 2; ++i) {
    int idx4 = tid + i * 256;
    int bb = idx4 >> 7, e4 = (idx4 & 127) << 2;
    *(float4*)&Gs[bb][e4] = *(const float4*)&G[((size_t)bb * Rn + r) * EMBn + e4];
  }
  __syncthreads();
  int wid = tid >> 6, lane = tid & 63;
#pragma unroll
  for (int i = 0; i < 4; ++i) {
    int rr = sc * 16 + wid * 4 + i;
    const float* vr = v + ((size_t)m * EMBn + hh * HSn + rr) * EMBn + lane * 8;
    float4 v0 = *(const float4*)vr;
    float4 v1 = *(const float4*)(vr + 4);
    float acc[Bn];
#pragma unroll
    for (int bb = 0; bb < Bn; ++bb) {
      const float* gp = &Gs[bb][lane * 8];
      float4 g0 = *(const float4*)gp;
      float4 g1 = *(const float4*)(gp + 4);
      acc[bb] = v0.x * g0.x + v0.y * g0.y + v0.z * g0.z + v0.w * g0.w +
                v1.x * g1.x + v1.y * g1.y + v1.z * g1.z + v1.w * g1.w;
    }
#pragma unroll
    for (int off = 1; off < 64; off <<= 1) {
#pragma unroll
      for (int bb = 0; bb < Bn; ++bb) acc[bb] += __shfl_xor(acc[bb], off, 64);
    }
    if (lane == 0) {
      float vbv = vb[(size_t)m * EMBn + hh * HSn + rr];
#pragma unroll
      for (int bb = 0; bb < Bn; ++bb) {
        out[(((size_t)bb * Hn + hh) * Mn + m) * HSn + rr] = acc[bb] + vbv;
      }
    }
  }
}

extern "C" void kernel_launch(void* const* d_in, const int* in_sizes, int n_in,
                              void* d_out, int out_size, void* d_ws,
                              size_t ws_size, hipStream_t stream) {
  const float* x = (const float*)d_in[0];
  const float* cells = (const float*)d_in[1];
  const float* q_w = (const float*)d_in[2];
  const float* q_b = (const float*)d_in[3];
  const float* v = (const float*)d_in[4];
  const float* vbp = (const float*)d_in[5];
  const float* ln_g = (const float*)d_in[6];
  const float* ln_b = (const float*)d_in[7];
  float* out = (float*)d_out;

  u16* hb = (u16*)d_ws;                             // 2 MB
  u16* htb = hb + (size_t)Bn * Ln * EMBn;           // 2 MB
  u16* Pb = htb + (size_t)Bn * Ln * EMBn;           // 256 KB
  float* pb = (float*)(Pb + (size_t)Rn * EMBn);     // 1 KB
  float* S = pb + Rn;                               // 2 MB
  float* G = S + (size_t)Bn * Rn * Ln;              // 2 MB
  unsigned* bar = (unsigned*)((char*)d_ws + BAR_OFF);

  hipMemsetAsync(bar, 0, 256, stream);

  void* args[] = {&x,  &ln_g, &ln_b, &cells, &q_w, &q_b, &hb,
                  &htb, &Pb,  &pb,   &S,     &G,   &bar};
  hipLaunchCooperativeKernel((const void*)persist_kernel, dim3(NBLK),
                             dim3(256), args, 0, stream);
  out_kernel<<<1024, 256, 0, stream>>>(v, vbp, G, out);
}